// Round 7
// baseline (312.740 us; speedup 1.0000x reference)
//
#include <hip/hip_runtime.h>

// YOLO detection head post-process.
// Input : x (B=64, C=255, 52, 52) f32   [C = 3 anchors * 85]
// Output: (B, 3*52*52, 85) f32
// out[((b*3+a)*2704 + y*52 + x)*85 + e]:
//   e==0: (sigmoid(v) + x) * 8
//   e==1: (sigmoid(v) + y) * 8
//   e==2: exp(v) * AW[a]
//   e==3: exp(v) * AH[a]
//   e>=4: sigmoid(v)
//
// R7: 4-tile in-block pipeline with RAW barriers + counted waits.
// HIP __syncthreads() drains vmcnt(0) at the barrier (m97), exposing all
// global-load latency once per tile. Here: issue tile t+1's loads between
// the LDS write and an explicit lgkmcnt(0)+s_barrier, so the loads stay
// in flight across the barrier and complete under tile t's transform.
// LDS 85*53*4 = 18,020 B; 256 threads (4 waves) -> 8 blocks/CU if VGPR<=64.

#define GG   2704      // 52*52
#define CH   85
#define LSTR 53        // odd -> transposed LDS reads are 2-way max (free)
#define NT   256
#define TPB  4         // row-tiles per block (rows 4j .. 4j+3)

__global__ __launch_bounds__(NT) void det_kernel(const float* __restrict__ in,
                                                 float* __restrict__ out) {
    __shared__ float lds[CH * LSTR];   // 18,020 B

    const int j   = blockIdx.x;   // row-group 0..12
    const int a   = blockIdx.y;   // anchor 0..2
    const int b   = blockIdx.z;   // batch 0..63
    const int tid = threadIdx.x;

    const float4* in4 = (const float4*)(in + ((size_t)b * 255 + (size_t)a * 85) * GG
                                           + (size_t)j * (TPB * 52));

    // ---- chunk geometry: 85 ch x 13 float4/row = 1105 chunks/tile ----
    // thread handles l = tid + 256k, k=0..3 for all, k=4 iff tid<81.
    // Both global and LDS offsets are invariant across tiles (global
    // advances by t*13 float4 = t*208 B -> folds to immediate offsets).
    int g0,g1,g2,g3,g4, l0,l1,l2,l3,l4;
    {
        int l, c, s4;
        l = tid;        c = l/13; s4 = l - c*13; g0 = c*676 + s4; l0 = c*LSTR + (s4<<2);
        l = tid +   NT; c = l/13; s4 = l - c*13; g1 = c*676 + s4; l1 = c*LSTR + (s4<<2);
        l = tid + 2*NT; c = l/13; s4 = l - c*13; g2 = c*676 + s4; l2 = c*LSTR + (s4<<2);
        l = tid + 3*NT; c = l/13; s4 = l - c*13; g3 = c*676 + s4; l3 = c*LSTR + (s4<<2);
        l = tid + 4*NT; c = l/13; s4 = l - c*13; g4 = c*676 + s4; l4 = c*LSTR + (s4<<2);
    }
    const bool x5 = (tid < 81);

    // ---- transform params (invariant; round-0 proven mapping) ----
    const int e  = tid % 85;
    const int s0 = tid / 85;           // 0,1,2
    const float AW[3] = {10.f, 16.f, 33.f};
    const float AH[3] = {13.f, 30.f, 23.f};
    const bool  isexp = (e == 2) | (e == 3);
    const float sgn   = isexp ? 1.f : -1.f;
    float scale;
    if (e < 2)       scale = 8.f;
    else if (e == 2) scale = AW[a];
    else if (e == 3) scale = AH[a];
    else             scale = 1.f;
    const float base0  = (e == 0) ? 8.f * (float)s0 : 0.f;
    const float adelta = (e == 0) ? 24.f : 0.f;
    const bool  doT    = (tid < 255);

    // ---- prologue: stage tile 0 into registers ----
    float4 v0_, v1_, v2_, v3_, v4_;
    v0_ = in4[g0]; v1_ = in4[g1]; v2_ = in4[g2]; v3_ = in4[g3];
    if (x5) v4_ = in4[g4];

    #pragma unroll
    for (int t = 0; t < TPB; ++t) {
        // B1: all waves done reading LDS for tile t-1 (reads are consumed
        // by VALU before stores, so none outstanding here).
        __builtin_amdgcn_s_barrier();

        // LDS write of tile t (compiler inserts vmcnt waits for v*_ here).
        // Scalar stores: LSTR=53 makes float4 LDS stores misaligned.
        {
            float* d;
            d = &lds[l0]; d[0]=v0_.x; d[1]=v0_.y; d[2]=v0_.z; d[3]=v0_.w;
            d = &lds[l1]; d[0]=v1_.x; d[1]=v1_.y; d[2]=v1_.z; d[3]=v1_.w;
            d = &lds[l2]; d[0]=v2_.x; d[1]=v2_.y; d[2]=v2_.z; d[3]=v2_.w;
            d = &lds[l3]; d[0]=v3_.x; d[1]=v3_.y; d[2]=v3_.z; d[3]=v3_.w;
            if (x5) { d = &lds[l4]; d[0]=v4_.x; d[1]=v4_.y; d[2]=v4_.z; d[3]=v4_.w; }
        }

        // Issue tile t+1's global loads NOW: they stay in flight across the
        // barrier below (no vmcnt drain) and land during transform t.
        if (t < TPB - 1) {
            v0_ = in4[g0 + (t+1)*13]; v1_ = in4[g1 + (t+1)*13];
            v2_ = in4[g2 + (t+1)*13]; v3_ = in4[g3 + (t+1)*13];
            if (x5) v4_ = in4[g4 + (t+1)*13];
        }

        // Commit LDS writes, then barrier: tile t visible to all waves.
        asm volatile("s_waitcnt lgkmcnt(0)" ::: "memory");
        __builtin_amdgcn_s_barrier();

        // ---- transform + store tile t ----
        if (doT) {
            const int y = j * TPB + t;
            float addend = base0 + ((e == 1) ? 8.f * (float)y : 0.f);
            float* op = out + ((size_t)((b * 3 + a) * GG) + (size_t)y * 52) * CH;
            int idx = e * LSTR + s0;
            #pragma unroll 2
            for (int o = tid; o < 52 * CH; o += 255, idx += 3) {   // 4420 outputs
                float v  = lds[idx];
                float tt = __expf(sgn * v);
                float w  = isexp ? tt : __builtin_amdgcn_rcpf(1.f + tt);
                op[o] = fmaf(scale, w, addend);
                addend += adelta;
            }
        }
    }
}

extern "C" void kernel_launch(void* const* d_in, const int* in_sizes, int n_in,
                              void* d_out, int out_size, void* d_ws, size_t ws_size,
                              hipStream_t stream) {
    const float* x = (const float*)d_in[0];
    float* out = (float*)d_out;
    dim3 grid(13, 3, 64);   // 13 row-groups x 3 anchors x 64 batch = 2496 blocks
    det_kernel<<<grid, NT, 0, stream>>>(x, out);
}